// Round 2
// baseline (105.559 us; speedup 1.0000x reference)
//
#include <hip/hip_runtime.h>

#define N_BINS 30
#define NCLASS 10
#define RPT 4            // rows per thread
#define BLOCK 256

// Workspace: [0]: 30 x u64 conf fixed-point (2^20 scale) totals
//            [240]: 30 x u64 packed (count<<32 | correct) totals
// Per-block LDS: 30 x u64 packed [conf_fx:32 | count:16 | correct:16]

__global__ void ece_zero_ws(unsigned long long* g_conf, unsigned long long* g_cc) {
    int i = threadIdx.x;
    if (i < N_BINS) { g_conf[i] = 0ull; g_cc[i] = 0ull; }
}

__device__ __forceinline__ void row_stats(const float* __restrict__ v,
                                          int lbl, int& bin,
                                          unsigned long long& pack) {
    float conf = v[0];
    int pred = 0;
    #pragma unroll
    for (int j = 1; j < NCLASS; ++j) {
        if (v[j] > conf) { conf = v[j]; pred = j; }
    }
    int b = (int)ceilf(conf * (float)N_BINS) - 1;
    bin = min(max(b, 0), N_BINS - 1);
    unsigned int fx = (unsigned int)(conf * 1048576.0f + 0.5f);   // 2^20 scale, rounded
    unsigned long long acc = (pred == lbl) ? 1ull : 0ull;
    pack = ((unsigned long long)fx << 32) | (1ull << 16) | acc;
}

__global__ __launch_bounds__(BLOCK) void ece_hist(
        const float* __restrict__ sm,
        const int*   __restrict__ labels,
        int n,
        unsigned long long* __restrict__ g_conf,
        unsigned long long* __restrict__ g_cc) {
    __shared__ unsigned long long s_hist[N_BINS];
    for (int i = threadIdx.x; i < N_BINS; i += blockDim.x) s_hist[i] = 0ull;
    __syncthreads();

    const long long r0 = ((long long)blockIdx.x * BLOCK + threadIdx.x) * RPT;

    int b0 = -1, b1 = -2, b2 = -3, b3 = -4;      // distinct sentinels -> no false merges
    unsigned long long p0 = 0, p1 = 0, p2 = 0, p3 = 0;
    bool v0 = false, v1 = false, v2 = false, v3 = false;

    if (r0 + RPT <= n) {
        // fast path: 40 contiguous floats = 10 x float4 (160B, 16B-aligned)
        const float4* p = reinterpret_cast<const float4*>(sm + r0 * NCLASS);
        float v[RPT * NCLASS];
        #pragma unroll
        for (int i = 0; i < 10; ++i) {
            float4 q = p[i];
            v[4*i+0] = q.x; v[4*i+1] = q.y; v[4*i+2] = q.z; v[4*i+3] = q.w;
        }
        const int4 lab = *reinterpret_cast<const int4*>(labels + r0);
        row_stats(v + 0,          lab.x, b0, p0); v0 = true;
        row_stats(v + NCLASS,     lab.y, b1, p1); v1 = true;
        row_stats(v + 2*NCLASS,   lab.z, b2, p2); v2 = true;
        row_stats(v + 3*NCLASS,   lab.w, b3, p3); v3 = true;
    } else if (r0 < n) {
        // tail path: per-row scalar
        float v[NCLASS];
        #pragma unroll
        for (int k = 0; k < RPT; ++k) {
            if (r0 + k < n) {
                #pragma unroll
                for (int j = 0; j < NCLASS; ++j) v[j] = sm[(r0 + k) * NCLASS + j];
                int lbl = labels[r0 + k];
                if (k == 0) { row_stats(v, lbl, b0, p0); v0 = true; }
                if (k == 1) { row_stats(v, lbl, b1, p1); v1 = true; }
                if (k == 2) { row_stats(v, lbl, b2, p2); v2 = true; }
                if (k == 3) { row_stats(v, lbl, b3, p3); v3 = true; }
            }
        }
    }

    // merge same-bin rows locally (fully static, no runtime-indexed arrays)
    if (v1 && b1 == b0) { p0 += p1; v1 = false; }
    if (v2) {
        if      (b2 == b0)       { p0 += p2; v2 = false; }
        else if (v1 && b2 == b1) { p1 += p2; v2 = false; }
    }
    if (v3) {
        if      (b3 == b0)       { p0 += p3; v3 = false; }
        else if (v1 && b3 == b1) { p1 += p3; v3 = false; }
        else if (v2 && b3 == b2) { p2 += p3; v3 = false; }
    }

    if (v0) atomicAdd(&s_hist[b0], p0);
    if (v1) atomicAdd(&s_hist[b1], p1);
    if (v2) atomicAdd(&s_hist[b2], p2);
    if (v3) atomicAdd(&s_hist[b3], p3);

    __syncthreads();

    if (threadIdx.x < N_BINS) {
        unsigned long long h = s_hist[threadIdx.x];
        if (h) {
            unsigned long long fxsum = h >> 32;
            unsigned long long cnt   = (h >> 16) & 0xFFFFull;
            unsigned long long acc   = h & 0xFFFFull;
            atomicAdd(&g_conf[threadIdx.x], fxsum);
            atomicAdd(&g_cc[threadIdx.x], (cnt << 32) | acc);
        }
    }
}

__global__ void ece_final(const unsigned long long* __restrict__ g_conf,
                          const unsigned long long* __restrict__ g_cc,
                          float* __restrict__ out,
                          float n_total) {
    if (blockIdx.x == 0 && threadIdx.x == 0) {
        float ece = 0.0f;
        for (int b = 0; b < N_BINS; ++b) {
            unsigned long long cc = g_cc[b];
            unsigned int cnt = (unsigned int)(cc >> 32);
            unsigned int cor = (unsigned int)(cc & 0xFFFFFFFFull);
            if (cnt > 0u) {
                float fcnt = (float)cnt;
                float avg_conf = (float)((double)g_conf[b] * (1.0 / 1048576.0)) / fcnt;
                float acc_in_bin = (float)cor / fcnt;
                float prop = fcnt / n_total;
                ece += fabsf(avg_conf - acc_in_bin) * prop;
            }
        }
        out[0] = ece;
    }
}

extern "C" void kernel_launch(void* const* d_in, const int* in_sizes, int n_in,
                              void* d_out, int out_size, void* d_ws, size_t ws_size,
                              hipStream_t stream) {
    const float* sm   = (const float*)d_in[0];
    const int* labels = (const int*)d_in[1];
    const int n = in_sizes[1];   // 4,000,000 rows

    unsigned long long* g_conf = (unsigned long long*)d_ws;
    unsigned long long* g_cc   = g_conf + N_BINS;

    ece_zero_ws<<<1, 64, 0, stream>>>(g_conf, g_cc);

    const int rows_per_block = BLOCK * RPT;
    const int grid = (n + rows_per_block - 1) / rows_per_block;
    ece_hist<<<grid, BLOCK, 0, stream>>>(sm, labels, n, g_conf, g_cc);

    ece_final<<<1, 64, 0, stream>>>(g_conf, g_cc, (float*)d_out, (float)n);
}